// Round 1
// baseline (665.646 us; speedup 1.0000x reference)
//
#include <hip/hip_runtime.h>
#include <hip/hip_bf16.h>
#include <math.h>

// Problem constants
#define N_      4
#define L_      256
#define M_      2
#define D_      768
#define H_      12
#define FF_     3072
#define DH_     64
#define LAYERS_ 4
#define BASE_   8          // N*M
#define T_      1032       // BASE_ + N*L
#define TP_     1152       // T_ padded to multiple of 128
#define KK_     258        // M + L
#define QS_     2304       // fused q|k|v row stride
#define PS_     264        // P LDS row stride (bf16)

typedef __bf16 bf16x8 __attribute__((ext_vector_type(8)));
typedef float  f32x4  __attribute__((ext_vector_type(4)));

__device__ __forceinline__ void async_load16(const __hip_bfloat16* g, __hip_bfloat16* l) {
  __builtin_amdgcn_global_load_lds(
      (const __attribute__((address_space(1))) unsigned int*)g,
      (__attribute__((address_space(3))) unsigned int*)l, 16, 0, 0);
}

// ---------------------------------------------------------------------------
// dst[N,K] bf16 = cast(transpose(src[K,N] fp32)). K,N multiples of 32.
// ---------------------------------------------------------------------------
__global__ __launch_bounds__(256) void transpose_cast_kernel(
    const float* __restrict__ src, __hip_bfloat16* __restrict__ dst, int K, int N) {
  __shared__ float tile[32][33];
  const int k0 = blockIdx.y * 32, n0 = blockIdx.x * 32;
  const int r = threadIdx.x >> 5, c = threadIdx.x & 31;
  #pragma unroll
  for (int i = 0; i < 4; ++i)
    tile[r + i * 8][c] = src[(size_t)(k0 + r + i * 8) * N + n0 + c];
  __syncthreads();
  #pragma unroll
  for (int i = 0; i < 4; ++i)
    dst[(size_t)(n0 + r + i * 8) * K + k0 + c] = __float2bfloat16(tile[c][r + i * 8]);
}

__global__ __launch_bounds__(256) void pack_bias_kernel(
    const float* __restrict__ bq, const float* __restrict__ bk,
    const float* __restrict__ bv, float* __restrict__ out) {
  int i = blockIdx.x * 256 + threadIdx.x;
  int l = i / QS_, j = i - l * QS_;
  float v;
  if (j < D_)            v = bq[l * D_ + j];
  else if (j < 2 * D_)   v = bk[l * D_ + (j - D_)];
  else                   v = bv[l * D_ + (j - 2 * D_)];
  out[i] = v;
}

// ---------------------------------------------------------------------------
__global__ __launch_bounds__(256) void embed_kernel(
    const int* __restrict__ ids, const float* __restrict__ memory,
    const float* __restrict__ emb, const float* __restrict__ pos,
    float* __restrict__ x, __hip_bfloat16* __restrict__ xb) {
  int row = blockIdx.x;
  const float *src, *p;
  if (row < BASE_) {
    src = memory + (long long)row * D_;
    p   = pos + (row & 1) * D_;
  } else {
    int i = row - BASE_;
    int tok = ids[i];
    src = emb + (long long)tok * D_;
    p   = pos + (M_ + (i & (L_ - 1))) * D_;
  }
  for (int d = threadIdx.x; d < D_; d += 256) {
    float v = src[d] + p[d];
    x[(long long)row * D_ + d]  = v;
    xb[(long long)row * D_ + d] = __float2bfloat16(v);
  }
}

// ---------------------------------------------------------------------------
// C = A[TP_,lda] @ Bt[N,lda]^T + bias (opt GELU).
// 128x128 block tile, 4 waves each 64x64 (4x4 x 16x16x32 MFMA), BK=64,
// double-buffered LDS (2-phase: stage t+1 issued before compute t),
// XOR-swizzled staging (pre-swizzled global source, linear LDS dest,
// swizzled ds_read) for dense conflict-free ds_read_b128.
// Split-K via blockIdx.z (each split KL long, partial outputs at
// C + z*TP_*N; bias added only by split 0).
// WVT: cols>=1536 go transposed to vt[col-1536][row] (V section of QKV).
// ---------------------------------------------------------------------------
template <int ACT, int WF32, int WBF16, int WVT, int KL>
__global__ __launch_bounds__(256) void gemm_mfma128(
    const __hip_bfloat16* __restrict__ A,   // [TP_][lda]
    const __hip_bfloat16* __restrict__ Bt,  // [N][lda]
    const float* __restrict__ bias,         // [N]
    float* __restrict__ C,                  // fp32 out (per-split)
    __hip_bfloat16* __restrict__ Cb,        // bf16 out
    __hip_bfloat16* __restrict__ vt,        // [768][TP_] transposed V out
    int N, int lda) {
  __shared__ __align__(16) __hip_bfloat16 As[2][128 * 64];
  __shared__ __align__(16) __hip_bfloat16 Bs[2][128 * 64];
  const int tid  = threadIdx.x;
  const int lane = tid & 63, wid = tid >> 6;
  const int ln   = lane & 15, qd = lane >> 4;
  const int wm   = wid >> 1, wn = wid & 1;
  const int r8   = lane >> 3;          // 0..7 row within wave's stage group
  const int c8   = (lane & 7) ^ r8;    // pre-swizzled global chunk index

  const size_t koff = (size_t)blockIdx.z * KL;
  const __hip_bfloat16* Ab = A  + ((size_t)blockIdx.y * 128 + wid * 8 + r8) * lda + koff + c8 * 8;
  const __hip_bfloat16* Bb = Bt + ((size_t)blockIdx.x * 128 + wid * 8 + r8) * lda + koff + c8 * 8;

  f32x4 acc[4][4] = {};

#define STAGE(buf, t) do {                                                    \
    const size_t kb_ = (size_t)(t) * 64;                                      \
    _Pragma("unroll")                                                         \
    for (int s_ = 0; s_ < 4; ++s_) {                                          \
      async_load16(Ab + (size_t)s_ * 32 * lda + kb_, &As[buf][(s_ * 32 + wid * 8) * 64]); \
      async_load16(Bb + (size_t)s_ * 32 * lda + kb_, &Bs[buf][(s_ * 32 + wid * 8) * 64]); \
    }                                                                         \
  } while (0)

#define COMPUTE(buf) do {                                                     \
    _Pragma("unroll")                                                         \
    for (int kk_ = 0; kk_ < 2; ++kk_) {                                       \
      bf16x8 af_[4], bf_[4];                                                  \
      _Pragma("unroll")                                                       \
      for (int m_ = 0; m_ < 4; ++m_) {                                        \
        int r_ = wm * 64 + m_ * 16 + ln;                                      \
        af_[m_] = *(const bf16x8*)&As[buf][r_ * 64 + ((kk_ * 4 + qd) ^ (r_ & 7)) * 8]; \
      }                                                                       \
      _Pragma("unroll")                                                       \
      for (int n_ = 0; n_ < 4; ++n_) {                                        \
        int r_ = wn * 64 + n_ * 16 + ln;                                      \
        bf_[n_] = *(const bf16x8*)&Bs[buf][r_ * 64 + ((kk_ * 4 + qd) ^ (r_ & 7)) * 8]; \
      }                                                                       \
      _Pragma("unroll")                                                       \
      for (int m_ = 0; m_ < 4; ++m_)                                          \
        _Pragma("unroll")                                                     \
        for (int n_ = 0; n_ < 4; ++n_)                                        \
          acc[m_][n_] = __builtin_amdgcn_mfma_f32_16x16x32_bf16(af_[m_], bf_[n_], acc[m_][n_], 0, 0, 0); \
    }                                                                         \
  } while (0)

  constexpr int NT = KL / 64;
  STAGE(0, 0);
  __syncthreads();
  for (int t = 0; t < NT; t += 2) {
    if (t + 1 < NT) STAGE(1, t + 1);
    COMPUTE(0);
    __syncthreads();            // drains vmcnt: buf1 (t+1) landed
    if (t + 1 < NT) {
      if (t + 2 < NT) STAGE(0, t + 2);
      COMPUTE(1);
      __syncthreads();
    }
  }
#undef STAGE
#undef COMPUTE

  #pragma unroll
  for (int mt = 0; mt < 4; ++mt) {
    #pragma unroll
    for (int nt = 0; nt < 4; ++nt) {
      const int col = blockIdx.x * 128 + wn * 64 + nt * 16 + ln;
      const float bv = (blockIdx.z == 0) ? bias[col] : 0.f;
      #pragma unroll
      for (int i = 0; i < 4; ++i) {
        const int row = blockIdx.y * 128 + wm * 64 + mt * 16 + qd * 4 + i;
        float v = acc[mt][nt][i] + bv;
        if (ACT) v = 0.5f * v * (1.f + erff(v * 0.70710678118654752f));
        if (WF32)
          C[(size_t)blockIdx.z * TP_ * N + (size_t)row * N + col] = v;
        if (WVT) {
          if (col < 2 * D_) Cb[(size_t)row * N + col] = __float2bfloat16(v);
          else              vt[(size_t)(col - 2 * D_) * TP_ + row] = __float2bfloat16(v);
        } else if (WBF16) {
          Cb[(size_t)row * N + col] = __float2bfloat16(v);
        }
      }
    }
  }
}

// ---------------------------------------------------------------------------
// MFMA attention. grid = (5 q-tiles, 12 heads, 4 batches), 4 waves/block.
// ---------------------------------------------------------------------------
__global__ __launch_bounds__(256) void attn_mfma(
    const __hip_bfloat16* __restrict__ qkv,  // [TP_][QS_]
    const __hip_bfloat16* __restrict__ vtb,  // [768][TP_]
    float* __restrict__ ctx) {               // [TP_][D_]
  __shared__ __align__(16) __hip_bfloat16 Ps[64][PS_];
  const int qt = blockIdx.x, h = blockIdx.y, b = blockIdx.z;
  const int tid = threadIdx.x;
  const int w = tid >> 6, lane = tid & 63, ln = lane & 15, qd = lane >> 4;

  bf16x8 aq0, aq1;
  {
    int j = qt * 64 + w * 16 + ln;
    int tok = (j < 256) ? (BASE_ + b * L_ + j)
            : ((j < KK_) ? (b * M_ + (j - 256)) : (b * M_));
    const __hip_bfloat16* qp = qkv + (size_t)tok * QS_ + h * DH_ + qd * 8;
    aq0 = *(const bf16x8*)qp;
    aq1 = *(const bf16x8*)(qp + 32);
  }

  f32x4 sa[17];
  #pragma unroll
  for (int nt = 0; nt < 17; ++nt) sa[nt] = (f32x4){0.f, 0.f, 0.f, 0.f};
  #pragma unroll
  for (int nt = 0; nt < 17; ++nt) {
    int key = nt * 16 + ln;
    int ktok = (key < 256) ? (BASE_ + b * L_ + key)
             : ((key < KK_) ? (b * M_ + (key - 256)) : (b * M_));
    const __hip_bfloat16* kp = qkv + (size_t)ktok * QS_ + D_ + h * DH_ + qd * 8;
    bf16x8 b0 = *(const bf16x8*)kp;
    bf16x8 b1 = *(const bf16x8*)(kp + 32);
    sa[nt] = __builtin_amdgcn_mfma_f32_16x16x32_bf16(aq0, b0, sa[nt], 0, 0, 0);
    sa[nt] = __builtin_amdgcn_mfma_f32_16x16x32_bf16(aq1, b1, sa[nt], 0, 0, 0);
  }

  #pragma unroll
  for (int i = 0; i < 4; ++i) {
    float v[17];
    #pragma unroll
    for (int nt = 0; nt < 17; ++nt) v[nt] = sa[nt][i] * 0.125f;
    float mx = -1e30f;
    #pragma unroll
    for (int nt = 0; nt < 16; ++nt) mx = fmaxf(mx, v[nt]);
    if (ln < 2) mx = fmaxf(mx, v[16]);
    #pragma unroll
    for (int m = 1; m < 16; m <<= 1) mx = fmaxf(mx, __shfl_xor(mx, m));
    float sum = 0.f;
    #pragma unroll
    for (int nt = 0; nt < 17; ++nt) {
      float e = (nt == 16 && ln >= 2) ? 0.f : __expf(v[nt] - mx);
      v[nt] = e;
      sum += e;
    }
    #pragma unroll
    for (int m = 1; m < 16; m <<= 1) sum += __shfl_xor(sum, m);
    float is = 1.f / sum;
    const int row = w * 16 + qd * 4 + i;
    #pragma unroll
    for (int nt = 0; nt < 17; ++nt)
      if (nt < 16 || ln < 2)
        Ps[row][nt * 16 + ln] = __float2bfloat16(v[nt] * is);
  }

  f32x4 oa[4] = {};
  #pragma unroll
  for (int k0 = 0; k0 < 8; ++k0) {
    bf16x8 ap = *(const bf16x8*)&Ps[w * 16 + ln][k0 * 32 + qd * 8];
    #pragma unroll
    for (int nt = 0; nt < 4; ++nt) {
      const __hip_bfloat16* vp = vtb + (size_t)(h * DH_ + nt * 16 + ln) * TP_
                               + BASE_ + b * L_ + k0 * 32 + qd * 8;
      bf16x8 bv = *(const bf16x8*)vp;
      oa[nt] = __builtin_amdgcn_mfma_f32_16x16x32_bf16(ap, bv, oa[nt], 0, 0, 0);
    }
  }
  {
    float p0[4], p1[4];
    #pragma unroll
    for (int i = 0; i < 4; ++i) {
      p0[i] = __bfloat162float(Ps[w * 16 + qd * 4 + i][256]);
      p1[i] = __bfloat162float(Ps[w * 16 + qd * 4 + i][257]);
    }
    #pragma unroll
    for (int nt = 0; nt < 4; ++nt) {
      const __hip_bfloat16* vp = vtb + (size_t)(h * DH_ + nt * 16 + ln) * TP_ + b * M_;
      float v0 = __bfloat162float(vp[0]);
      float v1 = __bfloat162float(vp[1]);
      #pragma unroll
      for (int i = 0; i < 4; ++i) oa[nt][i] += p0[i] * v0 + p1[i] * v1;
    }
  }

  #pragma unroll
  for (int i = 0; i < 4; ++i) {
    int j = qt * 64 + w * 16 + qd * 4 + i;
    if (j < KK_) {
      int tok = (j < 256) ? (BASE_ + b * L_ + j) : (b * M_ + (j - 256));
      #pragma unroll
      for (int nt = 0; nt < 4; ++nt)
        ctx[(size_t)tok * D_ + h * DH_ + nt * 16 + ln] = oa[nt][i];
    }
  }
}

// ---------------------------------------------------------------------------
// x = LN(x + sum_s delta_s); also writes bf16 copy.
// ---------------------------------------------------------------------------
template <int NS>
__global__ __launch_bounds__(256) void add_ln_kernel(
    float* __restrict__ x, const float* __restrict__ delta,
    const float* __restrict__ g, const float* __restrict__ b,
    __hip_bfloat16* __restrict__ xb) {
  __shared__ float sred[4];
  __shared__ float sbc;
  const int t = blockIdx.x, tid = threadIdx.x;
  float y[3];
  float s = 0.f;
  #pragma unroll
  for (int i = 0; i < 3; ++i) {
    int d = tid + i * 256;
    float v = x[(long long)t * D_ + d];
    #pragma unroll
    for (int s2 = 0; s2 < NS; ++s2)
      v += delta[(size_t)s2 * TP_ * D_ + (long long)t * D_ + d];
    y[i] = v;
    s += v;
  }
  #pragma unroll
  for (int o = 32; o > 0; o >>= 1) s += __shfl_down(s, o);
  if ((tid & 63) == 0) sred[tid >> 6] = s;
  __syncthreads();
  if (tid == 0) sbc = (sred[0] + sred[1] + sred[2] + sred[3]) * (1.f / D_);
  __syncthreads();
  const float mu = sbc;
  __syncthreads();
  float vs = 0.f;
  #pragma unroll
  for (int i = 0; i < 3; ++i) { float d = y[i] - mu; vs += d * d; }
  #pragma unroll
  for (int o = 32; o > 0; o >>= 1) vs += __shfl_down(vs, o);
  if ((tid & 63) == 0) sred[tid >> 6] = vs;
  __syncthreads();
  if (tid == 0) sbc = (sred[0] + sred[1] + sred[2] + sred[3]) * (1.f / D_);
  __syncthreads();
  const float inv = rsqrtf(sbc + 1e-5f);
  #pragma unroll
  for (int i = 0; i < 3; ++i) {
    int d = tid + i * 256;
    float v = (y[i] - mu) * inv * g[d] + b[d];
    x[(long long)t * D_ + d]  = v;
    xb[(long long)t * D_ + d] = __float2bfloat16(v);
  }
}

__global__ __launch_bounds__(256) void out_copy_kernel(
    const float* __restrict__ x, float* __restrict__ out, int n) {
  int i = blockIdx.x * 256 + threadIdx.x;
  if (i < n) out[i] = x[BASE_ * D_ + i];
}

// ---------------------------------------------------------------------------
extern "C" void kernel_launch(void* const* d_in, const int* in_sizes, int n_in,
                              void* d_out, int out_size, void* d_ws, size_t ws_size,
                              hipStream_t stream) {
  const int*   ids    = (const int*)  d_in[0];
  const float* memory = (const float*)d_in[1];
  const float* emb    = (const float*)d_in[2];
  const float* pos    = (const float*)d_in[3];
  const float* Wq     = (const float*)d_in[4];
  const float* bq     = (const float*)d_in[5];
  const float* Wk     = (const float*)d_in[6];
  const float* bk     = (const float*)d_in[7];
  const float* Wv     = (const float*)d_in[8];
  const float* bv     = (const float*)d_in[9];
  const float* W1     = (const float*)d_in[10];
  const float* b1     = (const float*)d_in[11];
  const float* W2     = (const float*)d_in[12];
  const float* b2     = (const float*)d_in[13];
  const float* g1     = (const float*)d_in[14];
  const float* be1    = (const float*)d_in[15];
  const float* g2     = (const float*)d_in[16];
  const float* be2    = (const float*)d_in[17];

  char* w = (char*)d_ws;
  float* x    = (float*)w;                      w += (size_t)TP_ * D_ * 4;
  float* cb   = (float*)w;                      w += (size_t)4 * TP_ * D_ * 4;  // 4 split-K partials
  float* bqkv = (float*)w;                      w += (size_t)LAYERS_ * QS_ * 4;
  __hip_bfloat16* xb    = (__hip_bfloat16*)w;   w += (size_t)TP_ * D_ * 2;
  __hip_bfloat16* qkvb  = (__hip_bfloat16*)w;   w += (size_t)TP_ * QS_ * 2;
  __hip_bfloat16* vtb   = (__hip_bfloat16*)w;   w += (size_t)D_ * TP_ * 2;
  __hip_bfloat16* hbb   = (__hip_bfloat16*)w;   w += (size_t)TP_ * FF_ * 2;
  __hip_bfloat16* Wqkvt = (__hip_bfloat16*)w;   w += (size_t)LAYERS_ * QS_ * D_ * 2;
  __hip_bfloat16* W1t   = (__hip_bfloat16*)w;   w += (size_t)LAYERS_ * FF_ * D_ * 2;
  __hip_bfloat16* W2t   = (__hip_bfloat16*)w;   w += (size_t)LAYERS_ * D_ * FF_ * 2;

  for (int i = 0; i < LAYERS_; ++i) {
    const size_t wo  = (size_t)i * D_ * D_;
    const size_t wo1 = (size_t)i * D_ * FF_;
    __hip_bfloat16* dqkv = Wqkvt + (size_t)i * QS_ * D_;
    transpose_cast_kernel<<<dim3(D_ / 32, D_ / 32), 256, 0, stream>>>(Wq + wo, dqkv,                       D_, D_);
    transpose_cast_kernel<<<dim3(D_ / 32, D_ / 32), 256, 0, stream>>>(Wk + wo, dqkv + (size_t)D_ * D_,     D_, D_);
    transpose_cast_kernel<<<dim3(D_ / 32, D_ / 32), 256, 0, stream>>>(Wv + wo, dqkv + (size_t)2 * D_ * D_, D_, D_);
    transpose_cast_kernel<<<dim3(FF_ / 32, D_ / 32), 256, 0, stream>>>(W1 + wo1, W1t + (size_t)i * FF_ * D_, D_, FF_);
    transpose_cast_kernel<<<dim3(D_ / 32, FF_ / 32), 256, 0, stream>>>(W2 + wo1, W2t + (size_t)i * D_ * FF_, FF_, D_);
  }
  pack_bias_kernel<<<LAYERS_ * QS_ / 256, 256, 0, stream>>>(bq, bk, bv, bqkv);

  embed_kernel<<<T_, 256, 0, stream>>>(ids, memory, emb, pos, x, xb);

  for (int i = 0; i < LAYERS_; ++i) {
    // QKV: [TP_,768] @ [2304,768]^T -> bf16 qkvb + transposed V
    gemm_mfma128<0, 0, 1, 1, 768><<<dim3(QS_ / 128, TP_ / 128, 1), 256, 0, stream>>>(
        xb, Wqkvt + (size_t)i * QS_ * D_, bqkv + i * QS_, nullptr, qkvb, vtb, QS_, D_);
    attn_mfma<<<dim3(5, H_, N_), 256, 0, stream>>>(qkvb, vtb, cb);
    add_ln_kernel<1><<<T_, 256, 0, stream>>>(x, cb, g1 + i * D_, be1 + i * D_, xb);
    // FFN1: [TP_,768] @ [3072,768]^T + GELU -> bf16 hbb
    gemm_mfma128<1, 0, 1, 0, 768><<<dim3(FF_ / 128, TP_ / 128, 1), 256, 0, stream>>>(
        xb, W1t + (size_t)i * FF_ * D_, b1 + i * FF_, nullptr, hbb, nullptr, FF_, D_);
    // FFN2: [TP_,3072] @ [768,3072]^T, split-K x4 -> 4 fp32 partials
    gemm_mfma128<0, 1, 0, 0, 768><<<dim3(D_ / 128, TP_ / 128, 4), 256, 0, stream>>>(
        hbb, W2t + (size_t)i * D_ * FF_, b2 + i * D_, cb, nullptr, nullptr, D_, FF_);
    add_ln_kernel<4><<<T_, 256, 0, stream>>>(x, cb, g2 + i * D_, be2 + i * D_, xb);
  }

  out_copy_kernel<<<(out_size + 255) / 256, 256, 0, stream>>>(x, (float*)d_out, out_size);
}

// Round 2
// 562.514 us; speedup vs baseline: 1.1833x; 1.1833x over previous
//
#include <hip/hip_runtime.h>
#include <hip/hip_bf16.h>
#include <math.h>

// Problem constants
#define N_      4
#define L_      256
#define M_      2
#define D_      768
#define H_      12
#define FF_     3072
#define DH_     64
#define LAYERS_ 4
#define BASE_   8          // N*M
#define T_      1032       // BASE_ + N*L
#define TP_     1088       // T_ padded to multiple of 64
#define KK_     258        // M + L
#define QS_     2304       // fused q|k|v row stride
#define PS_     264        // P LDS row stride (bf16): 264*2/4=132%32=4 -> 2-way (free)

typedef __bf16 bf16x8 __attribute__((ext_vector_type(8)));
typedef float  f32x4  __attribute__((ext_vector_type(4)));

__device__ __forceinline__ void async_load16(const __hip_bfloat16* g, __hip_bfloat16* l) {
  __builtin_amdgcn_global_load_lds(
      (const __attribute__((address_space(1))) unsigned int*)g,
      (__attribute__((address_space(3))) unsigned int*)l, 16, 0, 0);
}

// ---------------------------------------------------------------------------
// Fused preprocessing: all weight transposes (fp32 -> bf16, [K,N] -> [N,K]),
// QKV bias packing, and token/memory embedding — ONE dispatch.
// Segment map over blockIdx.x (branch is block-uniform):
//   [0,      6912)  : Wq/Wk/Wv transpose  (per layer 3 x 24x24 tiles)
//   [6912,  16128)  : W1 transpose        (per layer 24(K) x 96(N) tiles)
//   [16128, 25344)  : W2 transpose        (per layer 96(K) x 24(N) tiles)
//   [25344, 25380)  : bias pack           (36 x 256 = LAYERS*QS_)
//   [25380, 26412)  : embedding           (T_ rows)
// ---------------------------------------------------------------------------
#define PP_QKV_END_ 6912
#define PP_W1_END_  16128
#define PP_W2_END_  25344
#define PP_B_END_   25380
#define PP_TOTAL_   26412

__global__ __launch_bounds__(256) void preprocess_kernel(
    const float* __restrict__ Wq, const float* __restrict__ Wk,
    const float* __restrict__ Wv, const float* __restrict__ W1,
    const float* __restrict__ W2,
    const float* __restrict__ bq, const float* __restrict__ bk,
    const float* __restrict__ bv,
    const int* __restrict__ ids, const float* __restrict__ memory,
    const float* __restrict__ emb, const float* __restrict__ pos,
    __hip_bfloat16* __restrict__ Wqkvt, __hip_bfloat16* __restrict__ W1t,
    __hip_bfloat16* __restrict__ W2t, float* __restrict__ bqkv,
    float* __restrict__ x, __hip_bfloat16* __restrict__ xb) {
  __shared__ float tile[32][33];
  const int bid = blockIdx.x;
  const int tid = threadIdx.x;

  const float* src;
  __hip_bfloat16* dst;
  int K, N, bx, by;

  if (bid < PP_QKV_END_) {
    int l = bid / 1728, r = bid - l * 1728;
    int which = r / 576; r -= which * 576;
    by = r / 24; bx = r - by * 24;
    src = (which == 0 ? Wq : which == 1 ? Wk : Wv) + (size_t)l * D_ * D_;
    dst = Wqkvt + (size_t)l * QS_ * D_ + (size_t)which * D_ * D_;
    K = D_; N = D_;
  } else if (bid < PP_W1_END_) {
    int r0 = bid - PP_QKV_END_;
    int l = r0 / 2304, r = r0 - l * 2304;
    by = r / 96; bx = r - by * 96;          // K=D (24 tiles), N=FF (96 tiles)
    src = W1 + (size_t)l * D_ * FF_;
    dst = W1t + (size_t)l * FF_ * D_;
    K = D_; N = FF_;
  } else if (bid < PP_W2_END_) {
    int r0 = bid - PP_W1_END_;
    int l = r0 / 2304, r = r0 - l * 2304;
    by = r / 24; bx = r - by * 24;          // K=FF (96 tiles), N=D (24 tiles)
    src = W2 + (size_t)l * FF_ * D_;
    dst = W2t + (size_t)l * D_ * FF_;
    K = FF_; N = D_;
  } else if (bid < PP_B_END_) {
    int i = (bid - PP_W2_END_) * 256 + tid;
    int l = i / QS_, j = i - l * QS_;
    float v;
    if (j < D_)            v = bq[l * D_ + j];
    else if (j < 2 * D_)   v = bk[l * D_ + (j - D_)];
    else                   v = bv[l * D_ + (j - 2 * D_)];
    bqkv[i] = v;
    return;
  } else {
    int row = bid - PP_B_END_;
    const float *s2, *p;
    if (row < BASE_) {
      s2 = memory + (long long)row * D_;
      p  = pos + (row & 1) * D_;
    } else {
      int i = row - BASE_;
      int tok = ids[i];
      s2 = emb + (long long)tok * D_;
      p  = pos + (M_ + (i & (L_ - 1))) * D_;
    }
    for (int d = tid; d < D_; d += 256) {
      float v = s2[d] + p[d];
      x[(long long)row * D_ + d]  = v;
      xb[(long long)row * D_ + d] = __float2bfloat16(v);
    }
    return;
  }

  // 32x32 transpose tile: src[K,N] fp32 -> dst[N,K] bf16
  const int k0 = by * 32, n0 = bx * 32;
  const int r = tid >> 5, c = tid & 31;
  #pragma unroll
  for (int i = 0; i < 4; ++i)
    tile[r + i * 8][c] = src[(size_t)(k0 + r + i * 8) * N + n0 + c];
  __syncthreads();
  #pragma unroll
  for (int i = 0; i < 4; ++i)
    dst[(size_t)(n0 + r + i * 8) * K + k0 + c] = __float2bfloat16(tile[c][r + i * 8]);
}

// ---------------------------------------------------------------------------
// C = A[MP,K] @ Bt[N,K]^T + bias (opt GELU). 64x64 tile, BK=128, 4 waves 2x2.
// WVT: cols>=1536 go transposed to vt[col-1536][row] (V section of QKV gemm).
// ---------------------------------------------------------------------------
template <int ACT, int WF32, int WBF16, int WVT>
__global__ __launch_bounds__(256) void gemm_mfma(
    const __hip_bfloat16* __restrict__ A,   // [MP,K]
    const __hip_bfloat16* __restrict__ Bt,  // [N,K]
    const float* __restrict__ bias,         // [N]
    float* __restrict__ C,                  // fp32 out
    __hip_bfloat16* __restrict__ Cb,        // bf16 out
    __hip_bfloat16* __restrict__ vt,        // [768][TP_] transposed V out
    int N, int K) {
  __shared__ __align__(16) __hip_bfloat16 As[4][64][32];
  __shared__ __align__(16) __hip_bfloat16 Bs[4][64][32];
  const int tid  = threadIdx.x;
  const int lane = tid & 63, wid = tid >> 6;
  const int ln   = lane & 15, qd = lane >> 4;
  const int wm   = wid >> 1, wn = wid & 1;

  const size_t arow = (size_t)(blockIdx.y * 64 + wid * 16 + (lane >> 2)) * K + (lane & 3) * 8;
  const size_t brow = (size_t)(blockIdx.x * 64 + wid * 16 + (lane >> 2)) * K + (lane & 3) * 8;

  f32x4 acc[2][2] = {};
  for (int k0 = 0; k0 < K; k0 += 128) {
    #pragma unroll
    for (int s = 0; s < 4; ++s) {
      async_load16(A  + arow + k0 + s * 32, &As[s][wid * 16][0]);
      async_load16(Bt + brow + k0 + s * 32, &Bs[s][wid * 16][0]);
    }
    __syncthreads();
    #pragma unroll
    for (int s = 0; s < 4; ++s) {
      bf16x8 a0 = *(const bf16x8*)&As[s][wm * 32 + ln][qd * 8];
      bf16x8 a1 = *(const bf16x8*)&As[s][wm * 32 + 16 + ln][qd * 8];
      bf16x8 b0 = *(const bf16x8*)&Bs[s][wn * 32 + ln][qd * 8];
      bf16x8 b1 = *(const bf16x8*)&Bs[s][wn * 32 + 16 + ln][qd * 8];
      acc[0][0] = __builtin_amdgcn_mfma_f32_16x16x32_bf16(a0, b0, acc[0][0], 0, 0, 0);
      acc[0][1] = __builtin_amdgcn_mfma_f32_16x16x32_bf16(a0, b1, acc[0][1], 0, 0, 0);
      acc[1][0] = __builtin_amdgcn_mfma_f32_16x16x32_bf16(a1, b0, acc[1][0], 0, 0, 0);
      acc[1][1] = __builtin_amdgcn_mfma_f32_16x16x32_bf16(a1, b1, acc[1][1], 0, 0, 0);
    }
    __syncthreads();
  }
  #pragma unroll
  for (int mt = 0; mt < 2; ++mt) {
    #pragma unroll
    for (int nt = 0; nt < 2; ++nt) {
      const int col = blockIdx.x * 64 + wn * 32 + nt * 16 + ln;
      const float bv = bias[col];
      #pragma unroll
      for (int i = 0; i < 4; ++i) {
        const int row = blockIdx.y * 64 + wm * 32 + mt * 16 + qd * 4 + i;
        float v = acc[mt][nt][i] + bv;
        if (ACT) v = 0.5f * v * (1.f + erff(v * 0.70710678118654752f));
        if (WF32)  C[(size_t)row * N + col]  = v;
        if (WVT) {
          if (col < 2 * D_) Cb[(size_t)row * N + col] = __float2bfloat16(v);
          else              vt[(size_t)(col - 2 * D_) * TP_ + row] = __float2bfloat16(v);
        } else if (WBF16) {
          Cb[(size_t)row * N + col] = __float2bfloat16(v);
        }
      }
    }
  }
}

// ---------------------------------------------------------------------------
// MFMA attention. grid = (5 q-tiles, 12 heads, 4 batches), 4 waves/block.
// ---------------------------------------------------------------------------
__global__ __launch_bounds__(256) void attn_mfma(
    const __hip_bfloat16* __restrict__ qkv,  // [TP_][QS_]
    const __hip_bfloat16* __restrict__ vtb,  // [768][TP_]
    float* __restrict__ ctx) {               // [TP_][D_]
  __shared__ __align__(16) __hip_bfloat16 Ps[64][PS_];
  const int qt = blockIdx.x, h = blockIdx.y, b = blockIdx.z;
  const int tid = threadIdx.x;
  const int w = tid >> 6, lane = tid & 63, ln = lane & 15, qd = lane >> 4;

  bf16x8 aq0, aq1;
  {
    int j = qt * 64 + w * 16 + ln;
    int tok = (j < 256) ? (BASE_ + b * L_ + j)
            : ((j < KK_) ? (b * M_ + (j - 256)) : (b * M_));
    const __hip_bfloat16* qp = qkv + (size_t)tok * QS_ + h * DH_ + qd * 8;
    aq0 = *(const bf16x8*)qp;
    aq1 = *(const bf16x8*)(qp + 32);
  }

  f32x4 sa[17];
  #pragma unroll
  for (int nt = 0; nt < 17; ++nt) sa[nt] = (f32x4){0.f, 0.f, 0.f, 0.f};
  #pragma unroll
  for (int nt = 0; nt < 17; ++nt) {
    int key = nt * 16 + ln;
    int ktok = (key < 256) ? (BASE_ + b * L_ + key)
             : ((key < KK_) ? (b * M_ + (key - 256)) : (b * M_));
    const __hip_bfloat16* kp = qkv + (size_t)ktok * QS_ + D_ + h * DH_ + qd * 8;
    bf16x8 b0 = *(const bf16x8*)kp;
    bf16x8 b1 = *(const bf16x8*)(kp + 32);
    sa[nt] = __builtin_amdgcn_mfma_f32_16x16x32_bf16(aq0, b0, sa[nt], 0, 0, 0);
    sa[nt] = __builtin_amdgcn_mfma_f32_16x16x32_bf16(aq1, b1, sa[nt], 0, 0, 0);
  }

  #pragma unroll
  for (int i = 0; i < 4; ++i) {
    float v[17];
    #pragma unroll
    for (int nt = 0; nt < 17; ++nt) v[nt] = sa[nt][i] * 0.125f;
    float mx = -1e30f;
    #pragma unroll
    for (int nt = 0; nt < 16; ++nt) mx = fmaxf(mx, v[nt]);
    if (ln < 2) mx = fmaxf(mx, v[16]);
    #pragma unroll
    for (int m = 1; m < 16; m <<= 1) mx = fmaxf(mx, __shfl_xor(mx, m));
    float sum = 0.f;
    #pragma unroll
    for (int nt = 0; nt < 17; ++nt) {
      float e = (nt == 16 && ln >= 2) ? 0.f : __expf(v[nt] - mx);
      v[nt] = e;
      sum += e;
    }
    #pragma unroll
    for (int m = 1; m < 16; m <<= 1) sum += __shfl_xor(sum, m);
    float is = 1.f / sum;
    const int row = w * 16 + qd * 4 + i;
    #pragma unroll
    for (int nt = 0; nt < 17; ++nt)
      if (nt < 16 || ln < 2)
        Ps[row][nt * 16 + ln] = __float2bfloat16(v[nt] * is);
  }

  f32x4 oa[4] = {};
  #pragma unroll
  for (int k0 = 0; k0 < 8; ++k0) {
    bf16x8 ap = *(const bf16x8*)&Ps[w * 16 + ln][k0 * 32 + qd * 8];
    #pragma unroll
    for (int nt = 0; nt < 4; ++nt) {
      const __hip_bfloat16* vp = vtb + (size_t)(h * DH_ + nt * 16 + ln) * TP_
                               + BASE_ + b * L_ + k0 * 32 + qd * 8;
      bf16x8 bv = *(const bf16x8*)vp;
      oa[nt] = __builtin_amdgcn_mfma_f32_16x16x32_bf16(ap, bv, oa[nt], 0, 0, 0);
    }
  }
  {
    float p0[4], p1[4];
    #pragma unroll
    for (int i = 0; i < 4; ++i) {
      p0[i] = __bfloat162float(Ps[w * 16 + qd * 4 + i][256]);
      p1[i] = __bfloat162float(Ps[w * 16 + qd * 4 + i][257]);
    }
    #pragma unroll
    for (int nt = 0; nt < 4; ++nt) {
      const __hip_bfloat16* vp = vtb + (size_t)(h * DH_ + nt * 16 + ln) * TP_ + b * M_;
      float v0 = __bfloat162float(vp[0]);
      float v1 = __bfloat162float(vp[1]);
      #pragma unroll
      for (int i = 0; i < 4; ++i) oa[nt][i] += p0[i] * v0 + p1[i] * v1;
    }
  }

  #pragma unroll
  for (int i = 0; i < 4; ++i) {
    int j = qt * 64 + w * 16 + qd * 4 + i;
    if (j < KK_) {
      int tok = (j < 256) ? (BASE_ + b * L_ + j) : (b * M_ + (j - 256));
      #pragma unroll
      for (int nt = 0; nt < 4; ++nt)
        ctx[(size_t)tok * D_ + h * DH_ + nt * 16 + ln] = oa[nt][i];
    }
  }
}

// ---------------------------------------------------------------------------
// x = LN(x + delta); writes bf16 copy; optionally writes final output rows.
// ---------------------------------------------------------------------------
__global__ __launch_bounds__(256) void add_ln_kernel(
    float* __restrict__ x, const float* __restrict__ delta,
    const float* __restrict__ g, const float* __restrict__ b,
    __hip_bfloat16* __restrict__ xb, float* __restrict__ out) {
  __shared__ float sred[4];
  __shared__ float sbc;
  const int t = blockIdx.x, tid = threadIdx.x;
  float y[3];
  float s = 0.f;
  #pragma unroll
  for (int i = 0; i < 3; ++i) {
    int d = tid + i * 256;
    y[i] = x[(long long)t * D_ + d] + delta[(long long)t * D_ + d];
    s += y[i];
  }
  #pragma unroll
  for (int o = 32; o > 0; o >>= 1) s += __shfl_down(s, o);
  if ((tid & 63) == 0) sred[tid >> 6] = s;
  __syncthreads();
  if (tid == 0) sbc = (sred[0] + sred[1] + sred[2] + sred[3]) * (1.f / D_);
  __syncthreads();
  const float mu = sbc;
  __syncthreads();
  float vs = 0.f;
  #pragma unroll
  for (int i = 0; i < 3; ++i) { float d = y[i] - mu; vs += d * d; }
  #pragma unroll
  for (int o = 32; o > 0; o >>= 1) vs += __shfl_down(vs, o);
  if ((tid & 63) == 0) sred[tid >> 6] = vs;
  __syncthreads();
  if (tid == 0) sbc = (sred[0] + sred[1] + sred[2] + sred[3]) * (1.f / D_);
  __syncthreads();
  const float inv = rsqrtf(sbc + 1e-5f);
  #pragma unroll
  for (int i = 0; i < 3; ++i) {
    int d = tid + i * 256;
    float v = (y[i] - mu) * inv * g[d] + b[d];
    x[(long long)t * D_ + d]  = v;
    xb[(long long)t * D_ + d] = __float2bfloat16(v);
    if (out != nullptr && t >= BASE_)
      out[(size_t)(t - BASE_) * D_ + d] = v;
  }
}

// ---------------------------------------------------------------------------
extern "C" void kernel_launch(void* const* d_in, const int* in_sizes, int n_in,
                              void* d_out, int out_size, void* d_ws, size_t ws_size,
                              hipStream_t stream) {
  const int*   ids    = (const int*)  d_in[0];
  const float* memory = (const float*)d_in[1];
  const float* emb    = (const float*)d_in[2];
  const float* pos    = (const float*)d_in[3];
  const float* Wq     = (const float*)d_in[4];
  const float* bq     = (const float*)d_in[5];
  const float* Wk     = (const float*)d_in[6];
  const float* bk     = (const float*)d_in[7];
  const float* Wv     = (const float*)d_in[8];
  const float* bv     = (const float*)d_in[9];
  const float* W1     = (const float*)d_in[10];
  const float* b1     = (const float*)d_in[11];
  const float* W2     = (const float*)d_in[12];
  const float* b2     = (const float*)d_in[13];
  const float* g1     = (const float*)d_in[14];
  const float* be1    = (const float*)d_in[15];
  const float* g2     = (const float*)d_in[16];
  const float* be2    = (const float*)d_in[17];

  char* w = (char*)d_ws;
  float* x    = (float*)w;                      w += (size_t)TP_ * D_ * 4;
  float* cb   = (float*)w;                      w += (size_t)TP_ * D_ * 4;
  float* bqkv = (float*)w;                      w += (size_t)LAYERS_ * QS_ * 4;
  __hip_bfloat16* xb    = (__hip_bfloat16*)w;   w += (size_t)TP_ * D_ * 2;
  __hip_bfloat16* qkvb  = (__hip_bfloat16*)w;   w += (size_t)TP_ * QS_ * 2;
  __hip_bfloat16* vtb   = (__hip_bfloat16*)w;   w += (size_t)D_ * TP_ * 2;
  __hip_bfloat16* hbb   = (__hip_bfloat16*)w;   w += (size_t)TP_ * FF_ * 2;
  __hip_bfloat16* Wqkvt = (__hip_bfloat16*)w;   w += (size_t)LAYERS_ * QS_ * D_ * 2;
  __hip_bfloat16* W1t   = (__hip_bfloat16*)w;   w += (size_t)LAYERS_ * FF_ * D_ * 2;
  __hip_bfloat16* W2t   = (__hip_bfloat16*)w;   w += (size_t)LAYERS_ * D_ * FF_ * 2;

  // One dispatch: all weight transposes + bias pack + embedding
  preprocess_kernel<<<PP_TOTAL_, 256, 0, stream>>>(
      Wq, Wk, Wv, W1, W2, bq, bk, bv, ids, memory, emb, pos,
      Wqkvt, W1t, W2t, bqkv, x, xb);

  for (int i = 0; i < LAYERS_; ++i) {
    gemm_mfma<0, 0, 1, 1><<<dim3(QS_ / 64, TP_ / 64), 256, 0, stream>>>(
        xb, Wqkvt + (size_t)i * QS_ * D_, bqkv + i * QS_, nullptr, qkvb, vtb, QS_, D_);
    attn_mfma<<<dim3(5, H_, N_), 256, 0, stream>>>(qkvb, vtb, cb);
    add_ln_kernel<<<T_, 256, 0, stream>>>(x, cb, g1 + i * D_, be1 + i * D_, xb, nullptr);
    gemm_mfma<1, 0, 1, 0><<<dim3(FF_ / 64, TP_ / 64), 256, 0, stream>>>(
        xb, W1t + (size_t)i * FF_ * D_, b1 + i * FF_, nullptr, hbb, nullptr, FF_, D_);
    gemm_mfma<0, 1, 0, 0><<<dim3(D_ / 64, TP_ / 64), 256, 0, stream>>>(
        hbb, W2t + (size_t)i * D_ * FF_, b2 + i * D_, cb, nullptr, nullptr, D_, FF_);
    add_ln_kernel<<<T_, 256, 0, stream>>>(
        x, cb, g2 + i * D_, be2 + i * D_, xb,
        (i == LAYERS_ - 1) ? (float*)d_out : nullptr);
  }
}

// Round 3
// 544.517 us; speedup vs baseline: 1.2225x; 1.0331x over previous
//
#include <hip/hip_runtime.h>
#include <hip/hip_bf16.h>
#include <math.h>

// Problem constants
#define N_      4
#define L_      256
#define M_      2
#define D_      768
#define H_      12
#define FF_     3072
#define DH_     64
#define LAYERS_ 4
#define BASE_   8          // N*M
#define T_      1032       // BASE_ + N*L
#define TP_     1088       // T_ padded to multiple of 64
#define KK_     258        // M + L
#define QS_     2304       // fused q|k|v row stride
#define PS_     264        // P LDS row stride (bf16)

typedef __bf16 bf16x8 __attribute__((ext_vector_type(8)));
typedef float  f32x4  __attribute__((ext_vector_type(4)));

__device__ __forceinline__ void async_load16(const __hip_bfloat16* g, __hip_bfloat16* l) {
  __builtin_amdgcn_global_load_lds(
      (const __attribute__((address_space(1))) unsigned int*)g,
      (__attribute__((address_space(3))) unsigned int*)l, 16, 0, 0);
}

// ---------------------------------------------------------------------------
// Fused preprocessing: all weight transposes (fp32 -> bf16, [K,N] -> [N,K]),
// QKV bias packing, and token/memory embedding — ONE dispatch.
// ---------------------------------------------------------------------------
#define PP_QKV_END_ 6912
#define PP_W1_END_  16128
#define PP_W2_END_  25344
#define PP_B_END_   25380
#define PP_TOTAL_   26412

__global__ __launch_bounds__(256) void preprocess_kernel(
    const float* __restrict__ Wq, const float* __restrict__ Wk,
    const float* __restrict__ Wv, const float* __restrict__ W1,
    const float* __restrict__ W2,
    const float* __restrict__ bq, const float* __restrict__ bk,
    const float* __restrict__ bv,
    const int* __restrict__ ids, const float* __restrict__ memory,
    const float* __restrict__ emb, const float* __restrict__ pos,
    __hip_bfloat16* __restrict__ Wqkvt, __hip_bfloat16* __restrict__ W1t,
    __hip_bfloat16* __restrict__ W2t, float* __restrict__ bqkv,
    float* __restrict__ x, __hip_bfloat16* __restrict__ xb) {
  __shared__ float tile[32][33];
  const int bid = blockIdx.x;
  const int tid = threadIdx.x;

  const float* src;
  __hip_bfloat16* dst;
  int K, N, bx, by;

  if (bid < PP_QKV_END_) {
    int l = bid / 1728, r = bid - l * 1728;
    int which = r / 576; r -= which * 576;
    by = r / 24; bx = r - by * 24;
    src = (which == 0 ? Wq : which == 1 ? Wk : Wv) + (size_t)l * D_ * D_;
    dst = Wqkvt + (size_t)l * QS_ * D_ + (size_t)which * D_ * D_;
    K = D_; N = D_;
  } else if (bid < PP_W1_END_) {
    int r0 = bid - PP_QKV_END_;
    int l = r0 / 2304, r = r0 - l * 2304;
    by = r / 96; bx = r - by * 96;
    src = W1 + (size_t)l * D_ * FF_;
    dst = W1t + (size_t)l * FF_ * D_;
    K = D_; N = FF_;
  } else if (bid < PP_W2_END_) {
    int r0 = bid - PP_W1_END_;
    int l = r0 / 2304, r = r0 - l * 2304;
    by = r / 24; bx = r - by * 24;
    src = W2 + (size_t)l * FF_ * D_;
    dst = W2t + (size_t)l * D_ * FF_;
    K = FF_; N = D_;
  } else if (bid < PP_B_END_) {
    int i = (bid - PP_W2_END_) * 256 + tid;
    int l = i / QS_, j = i - l * QS_;
    float v;
    if (j < D_)            v = bq[l * D_ + j];
    else if (j < 2 * D_)   v = bk[l * D_ + (j - D_)];
    else                   v = bv[l * D_ + (j - 2 * D_)];
    bqkv[i] = v;
    return;
  } else {
    int row = bid - PP_B_END_;
    const float *s2, *p;
    if (row < BASE_) {
      s2 = memory + (long long)row * D_;
      p  = pos + (row & 1) * D_;
    } else {
      int i = row - BASE_;
      int tok = ids[i];
      s2 = emb + (long long)tok * D_;
      p  = pos + (M_ + (i & (L_ - 1))) * D_;
    }
    for (int d = tid; d < D_; d += 256) {
      float v = s2[d] + p[d];
      x[(long long)row * D_ + d]  = v;
      xb[(long long)row * D_ + d] = __float2bfloat16(v);
    }
    return;
  }

  const int k0 = by * 32, n0 = bx * 32;
  const int r = tid >> 5, c = tid & 31;
  #pragma unroll
  for (int i = 0; i < 4; ++i)
    tile[r + i * 8][c] = src[(size_t)(k0 + r + i * 8) * N + n0 + c];
  __syncthreads();
  #pragma unroll
  for (int i = 0; i < 4; ++i)
    dst[(size_t)(n0 + r + i * 8) * K + k0 + c] = __float2bfloat16(tile[c][r + i * 8]);
}

// ---------------------------------------------------------------------------
// C = A[MP,Ktot] @ Bt[N,Ktot]^T + bias (opt GELU). 64x64 tile, BK=128,
// 4 waves 2x2, double-buffered LDS (stage t+1 issued before compute t;
// the single __syncthreads per iter drains vmcnt so t+1 is landed after it).
// NSPLIT: K split across blockIdx.z; fp32 partials at C + z*TP_*N,
// bias added only by split 0.
// WVT: cols>=1536 go transposed to vt[col-1536][row] (V section of QKV gemm).
// ---------------------------------------------------------------------------
template <int ACT, int WF32, int WBF16, int WVT, int NSPLIT>
__global__ __launch_bounds__(256) void gemm_mfma(
    const __hip_bfloat16* __restrict__ A,   // [MP,Ktot]
    const __hip_bfloat16* __restrict__ Bt,  // [N,Ktot]
    const float* __restrict__ bias,         // [N]
    float* __restrict__ C,                  // fp32 out (per-split)
    __hip_bfloat16* __restrict__ Cb,        // bf16 out
    __hip_bfloat16* __restrict__ vt,        // [768][TP_] transposed V out
    int N, int Ktot) {
  __shared__ __align__(16) __hip_bfloat16 As[2][4][64][32];
  __shared__ __align__(16) __hip_bfloat16 Bs[2][4][64][32];
  const int tid  = threadIdx.x;
  const int lane = tid & 63, wid = tid >> 6;
  const int ln   = lane & 15, qd = lane >> 4;
  const int wm   = wid >> 1, wn = wid & 1;

  const int K = Ktot / NSPLIT;
  const size_t koff = (size_t)blockIdx.z * K;

  const size_t arow = (size_t)(blockIdx.y * 64 + wid * 16 + (lane >> 2)) * Ktot + koff + (lane & 3) * 8;
  const size_t brow = (size_t)(blockIdx.x * 64 + wid * 16 + (lane >> 2)) * Ktot + koff + (lane & 3) * 8;

  f32x4 acc[2][2] = {};

#define STAGE(b, k0) do {                                                     \
    _Pragma("unroll")                                                         \
    for (int s_ = 0; s_ < 4; ++s_) {                                          \
      async_load16(A  + arow + (k0) + s_ * 32, &As[b][s_][wid * 16][0]);      \
      async_load16(Bt + brow + (k0) + s_ * 32, &Bs[b][s_][wid * 16][0]);      \
    }                                                                         \
  } while (0)

  STAGE(0, 0);
  __syncthreads();
  int buf = 0;
  for (int k0 = 0; k0 < K; k0 += 128) {
    if (k0 + 128 < K) STAGE(buf ^ 1, k0 + 128);
    #pragma unroll
    for (int s = 0; s < 4; ++s) {
      bf16x8 a0 = *(const bf16x8*)&As[buf][s][wm * 32 + ln][qd * 8];
      bf16x8 a1 = *(const bf16x8*)&As[buf][s][wm * 32 + 16 + ln][qd * 8];
      bf16x8 b0 = *(const bf16x8*)&Bs[buf][s][wn * 32 + ln][qd * 8];
      bf16x8 b1 = *(const bf16x8*)&Bs[buf][s][wn * 32 + 16 + ln][qd * 8];
      acc[0][0] = __builtin_amdgcn_mfma_f32_16x16x32_bf16(a0, b0, acc[0][0], 0, 0, 0);
      acc[0][1] = __builtin_amdgcn_mfma_f32_16x16x32_bf16(a0, b1, acc[0][1], 0, 0, 0);
      acc[1][0] = __builtin_amdgcn_mfma_f32_16x16x32_bf16(a1, b0, acc[1][0], 0, 0, 0);
      acc[1][1] = __builtin_amdgcn_mfma_f32_16x16x32_bf16(a1, b1, acc[1][1], 0, 0, 0);
    }
    __syncthreads();   // drains vmcnt: next tile landed; buf safe to overwrite
    buf ^= 1;
  }
#undef STAGE

  #pragma unroll
  for (int mt = 0; mt < 2; ++mt) {
    #pragma unroll
    for (int nt = 0; nt < 2; ++nt) {
      const int col = blockIdx.x * 64 + wn * 32 + nt * 16 + ln;
      const float bv = (NSPLIT == 1 || blockIdx.z == 0) ? bias[col] : 0.f;
      #pragma unroll
      for (int i = 0; i < 4; ++i) {
        const int row = blockIdx.y * 64 + wm * 32 + mt * 16 + qd * 4 + i;
        float v = acc[mt][nt][i] + bv;
        if (ACT) v = 0.5f * v * (1.f + erff(v * 0.70710678118654752f));
        if (WF32)
          C[(size_t)blockIdx.z * TP_ * N + (size_t)row * N + col] = v;
        if (WVT) {
          if (col < 2 * D_) Cb[(size_t)row * N + col] = __float2bfloat16(v);
          else              vt[(size_t)(col - 2 * D_) * TP_ + row] = __float2bfloat16(v);
        } else if (WBF16) {
          Cb[(size_t)row * N + col] = __float2bfloat16(v);
        }
      }
    }
  }
}

// ---------------------------------------------------------------------------
// MFMA attention. grid = (5 q-tiles, 12 heads, 4 batches), 4 waves/block.
// ---------------------------------------------------------------------------
__global__ __launch_bounds__(256) void attn_mfma(
    const __hip_bfloat16* __restrict__ qkv,  // [TP_][QS_]
    const __hip_bfloat16* __restrict__ vtb,  // [768][TP_]
    float* __restrict__ ctx) {               // [TP_][D_]
  __shared__ __align__(16) __hip_bfloat16 Ps[64][PS_];
  const int qt = blockIdx.x, h = blockIdx.y, b = blockIdx.z;
  const int tid = threadIdx.x;
  const int w = tid >> 6, lane = tid & 63, ln = lane & 15, qd = lane >> 4;

  bf16x8 aq0, aq1;
  {
    int j = qt * 64 + w * 16 + ln;
    int tok = (j < 256) ? (BASE_ + b * L_ + j)
            : ((j < KK_) ? (b * M_ + (j - 256)) : (b * M_));
    const __hip_bfloat16* qp = qkv + (size_t)tok * QS_ + h * DH_ + qd * 8;
    aq0 = *(const bf16x8*)qp;
    aq1 = *(const bf16x8*)(qp + 32);
  }

  f32x4 sa[17];
  #pragma unroll
  for (int nt = 0; nt < 17; ++nt) sa[nt] = (f32x4){0.f, 0.f, 0.f, 0.f};
  #pragma unroll
  for (int nt = 0; nt < 17; ++nt) {
    int key = nt * 16 + ln;
    int ktok = (key < 256) ? (BASE_ + b * L_ + key)
             : ((key < KK_) ? (b * M_ + (key - 256)) : (b * M_));
    const __hip_bfloat16* kp = qkv + (size_t)ktok * QS_ + D_ + h * DH_ + qd * 8;
    bf16x8 b0 = *(const bf16x8*)kp;
    bf16x8 b1 = *(const bf16x8*)(kp + 32);
    sa[nt] = __builtin_amdgcn_mfma_f32_16x16x32_bf16(aq0, b0, sa[nt], 0, 0, 0);
    sa[nt] = __builtin_amdgcn_mfma_f32_16x16x32_bf16(aq1, b1, sa[nt], 0, 0, 0);
  }

  #pragma unroll
  for (int i = 0; i < 4; ++i) {
    float v[17];
    #pragma unroll
    for (int nt = 0; nt < 17; ++nt) v[nt] = sa[nt][i] * 0.125f;
    float mx = -1e30f;
    #pragma unroll
    for (int nt = 0; nt < 16; ++nt) mx = fmaxf(mx, v[nt]);
    if (ln < 2) mx = fmaxf(mx, v[16]);
    #pragma unroll
    for (int m = 1; m < 16; m <<= 1) mx = fmaxf(mx, __shfl_xor(mx, m));
    float sum = 0.f;
    #pragma unroll
    for (int nt = 0; nt < 17; ++nt) {
      float e = (nt == 16 && ln >= 2) ? 0.f : __expf(v[nt] - mx);
      v[nt] = e;
      sum += e;
    }
    #pragma unroll
    for (int m = 1; m < 16; m <<= 1) sum += __shfl_xor(sum, m);
    float is = 1.f / sum;
    const int row = w * 16 + qd * 4 + i;
    #pragma unroll
    for (int nt = 0; nt < 17; ++nt)
      if (nt < 16 || ln < 2)
        Ps[row][nt * 16 + ln] = __float2bfloat16(v[nt] * is);
  }

  f32x4 oa[4] = {};
  #pragma unroll
  for (int k0 = 0; k0 < 8; ++k0) {
    bf16x8 ap = *(const bf16x8*)&Ps[w * 16 + ln][k0 * 32 + qd * 8];
    #pragma unroll
    for (int nt = 0; nt < 4; ++nt) {
      const __hip_bfloat16* vp = vtb + (size_t)(h * DH_ + nt * 16 + ln) * TP_
                               + BASE_ + b * L_ + k0 * 32 + qd * 8;
      bf16x8 bv = *(const bf16x8*)vp;
      oa[nt] = __builtin_amdgcn_mfma_f32_16x16x32_bf16(ap, bv, oa[nt], 0, 0, 0);
    }
  }
  {
    float p0[4], p1[4];
    #pragma unroll
    for (int i = 0; i < 4; ++i) {
      p0[i] = __bfloat162float(Ps[w * 16 + qd * 4 + i][256]);
      p1[i] = __bfloat162float(Ps[w * 16 + qd * 4 + i][257]);
    }
    #pragma unroll
    for (int nt = 0; nt < 4; ++nt) {
      const __hip_bfloat16* vp = vtb + (size_t)(h * DH_ + nt * 16 + ln) * TP_ + b * M_;
      float v0 = __bfloat162float(vp[0]);
      float v1 = __bfloat162float(vp[1]);
      #pragma unroll
      for (int i = 0; i < 4; ++i) oa[nt][i] += p0[i] * v0 + p1[i] * v1;
    }
  }

  #pragma unroll
  for (int i = 0; i < 4; ++i) {
    int j = qt * 64 + w * 16 + qd * 4 + i;
    if (j < KK_) {
      int tok = (j < 256) ? (BASE_ + b * L_ + j) : (b * M_ + (j - 256));
      #pragma unroll
      for (int nt = 0; nt < 4; ++nt)
        ctx[(size_t)tok * D_ + h * DH_ + nt * 16 + ln] = oa[nt][i];
    }
  }
}

// ---------------------------------------------------------------------------
// x = LN(x + sum_s delta_s); bf16 copy; optionally writes final output rows.
// ---------------------------------------------------------------------------
template <int NS>
__global__ __launch_bounds__(256) void add_ln_kernel(
    float* __restrict__ x, const float* __restrict__ delta,
    const float* __restrict__ g, const float* __restrict__ b,
    __hip_bfloat16* __restrict__ xb, float* __restrict__ out) {
  __shared__ float sred[4];
  __shared__ float sbc;
  const int t = blockIdx.x, tid = threadIdx.x;
  float y[3];
  float s = 0.f;
  #pragma unroll
  for (int i = 0; i < 3; ++i) {
    int d = tid + i * 256;
    float v = x[(long long)t * D_ + d];
    #pragma unroll
    for (int s2 = 0; s2 < NS; ++s2)
      v += delta[(size_t)s2 * TP_ * D_ + (long long)t * D_ + d];
    y[i] = v;
    s += v;
  }
  #pragma unroll
  for (int o = 32; o > 0; o >>= 1) s += __shfl_down(s, o);
  if ((tid & 63) == 0) sred[tid >> 6] = s;
  __syncthreads();
  if (tid == 0) sbc = (sred[0] + sred[1] + sred[2] + sred[3]) * (1.f / D_);
  __syncthreads();
  const float mu = sbc;
  __syncthreads();
  float vs = 0.f;
  #pragma unroll
  for (int i = 0; i < 3; ++i) { float d = y[i] - mu; vs += d * d; }
  #pragma unroll
  for (int o = 32; o > 0; o >>= 1) vs += __shfl_down(vs, o);
  if ((tid & 63) == 0) sred[tid >> 6] = vs;
  __syncthreads();
  if (tid == 0) sbc = (sred[0] + sred[1] + sred[2] + sred[3]) * (1.f / D_);
  __syncthreads();
  const float inv = rsqrtf(sbc + 1e-5f);
  #pragma unroll
  for (int i = 0; i < 3; ++i) {
    int d = tid + i * 256;
    float v = (y[i] - mu) * inv * g[d] + b[d];
    x[(long long)t * D_ + d]  = v;
    xb[(long long)t * D_ + d] = __float2bfloat16(v);
    if (out != nullptr && t >= BASE_)
      out[(size_t)(t - BASE_) * D_ + d] = v;
  }
}

// ---------------------------------------------------------------------------
extern "C" void kernel_launch(void* const* d_in, const int* in_sizes, int n_in,
                              void* d_out, int out_size, void* d_ws, size_t ws_size,
                              hipStream_t stream) {
  const int*   ids    = (const int*)  d_in[0];
  const float* memory = (const float*)d_in[1];
  const float* emb    = (const float*)d_in[2];
  const float* pos    = (const float*)d_in[3];
  const float* Wq     = (const float*)d_in[4];
  const float* bq     = (const float*)d_in[5];
  const float* Wk     = (const float*)d_in[6];
  const float* bk     = (const float*)d_in[7];
  const float* Wv     = (const float*)d_in[8];
  const float* bv     = (const float*)d_in[9];
  const float* W1     = (const float*)d_in[10];
  const float* b1     = (const float*)d_in[11];
  const float* W2     = (const float*)d_in[12];
  const float* b2     = (const float*)d_in[13];
  const float* g1     = (const float*)d_in[14];
  const float* be1    = (const float*)d_in[15];
  const float* g2     = (const float*)d_in[16];
  const float* be2    = (const float*)d_in[17];

  char* w = (char*)d_ws;
  float* x    = (float*)w;                      w += (size_t)TP_ * D_ * 4;
  float* cb   = (float*)w;                      w += (size_t)2 * TP_ * D_ * 4;  // 2 split-K partials
  float* bqkv = (float*)w;                      w += (size_t)LAYERS_ * QS_ * 4;
  __hip_bfloat16* xb    = (__hip_bfloat16*)w;   w += (size_t)TP_ * D_ * 2;
  __hip_bfloat16* qkvb  = (__hip_bfloat16*)w;   w += (size_t)TP_ * QS_ * 2;
  __hip_bfloat16* vtb   = (__hip_bfloat16*)w;   w += (size_t)D_ * TP_ * 2;
  __hip_bfloat16* hbb   = (__hip_bfloat16*)w;   w += (size_t)TP_ * FF_ * 2;
  __hip_bfloat16* Wqkvt = (__hip_bfloat16*)w;   w += (size_t)LAYERS_ * QS_ * D_ * 2;
  __hip_bfloat16* W1t   = (__hip_bfloat16*)w;   w += (size_t)LAYERS_ * FF_ * D_ * 2;
  __hip_bfloat16* W2t   = (__hip_bfloat16*)w;   w += (size_t)LAYERS_ * D_ * FF_ * 2;

  preprocess_kernel<<<PP_TOTAL_, 256, 0, stream>>>(
      Wq, Wk, Wv, W1, W2, bq, bk, bv, ids, memory, emb, pos,
      Wqkvt, W1t, W2t, bqkv, x, xb);

  for (int i = 0; i < LAYERS_; ++i) {
    gemm_mfma<0, 0, 1, 1, 1><<<dim3(QS_ / 64, TP_ / 64), 256, 0, stream>>>(
        xb, Wqkvt + (size_t)i * QS_ * D_, bqkv + i * QS_, nullptr, qkvb, vtb, QS_, D_);
    attn_mfma<<<dim3(5, H_, N_), 256, 0, stream>>>(qkvb, vtb, cb);
    add_ln_kernel<1><<<T_, 256, 0, stream>>>(x, cb, g1 + i * D_, be1 + i * D_, xb, nullptr);
    gemm_mfma<1, 0, 1, 0, 1><<<dim3(FF_ / 64, TP_ / 64), 256, 0, stream>>>(
        xb, W1t + (size_t)i * FF_ * D_, b1 + i * FF_, nullptr, hbb, nullptr, FF_, D_);
    gemm_mfma<0, 1, 0, 0, 2><<<dim3(D_ / 64, TP_ / 64, 2), 256, 0, stream>>>(
        hbb, W2t + (size_t)i * D_ * FF_, b2 + i * D_, cb, nullptr, nullptr, D_, FF_);
    add_ln_kernel<2><<<T_, 256, 0, stream>>>(
        x, cb, g2 + i * D_, be2 + i * D_, xb,
        (i == LAYERS_ - 1) ? (float*)d_out : nullptr);
  }
}